// Round 5
// baseline (13352.277 us; speedup 1.0000x reference)
//
#include <hip/hip_runtime.h>
#include <math.h>

typedef __attribute__((ext_vector_type(8))) short v8s;
typedef __attribute__((ext_vector_type(4))) float v4f;

#define AP 136              // padded LDS row stride (shorts); 272 B rows keep 16B align
#define OFF_W3 0
#define OFF_WI 524288
#define OFF_W1 528384
#define OFF_W2 544768
#define OFF_WR 561152
#define LO     565248       // lo-residual region offset (shorts)
#define WF_TOTAL2 1130496   // hi+lo regions (shorts, 2.26 MB) -- proven to fit (r4)
#define KBUF_BYTE 2260992   // float kbuf[16 bg][2 par][2048]  (256 KB)
#define CNT_BYTE  2523136   // uint cnt[16 bg] @ 32 B spacing  (512 B)
#define WS_NEED   2523648

static __device__ __forceinline__ float bf2f(unsigned short s){
    union { unsigned u; float f; } v; v.u = ((unsigned)s) << 16; return v.f;
}
static __device__ __forceinline__ unsigned short f2bf(float f){
    union { float ff; unsigned u; } v; v.ff = f;
    return (unsigned short)((v.u + 0x7FFFu + ((v.u >> 16) & 1u)) >> 16);
}
// triple split: v = h + m + l + eps, |eps| <= 2^-27 |v|
static __device__ __forceinline__ void split3(float v, unsigned short& h,
                                              unsigned short& m, unsigned short& l){
    h = f2bf(v);  float r1 = v - bf2f(h);
    m = f2bf(r1); float r2 = r1 - bf2f(m);
    l = f2bf(r2);
}
static __device__ __forceinline__ float softplus_f(float x){
    return (x > 20.0f) ? x : log1pf(expf(x));
}
static __device__ __forceinline__ float tanh_f(float x){
    float xc = fminf(fmaxf(x, -9.0f), 9.0f);
    float t = __builtin_amdgcn_exp2f(xc * 2.8853900817779268f); // e^{2x}
    float d = t + 1.0f;
    float r = __builtin_amdgcn_rcpf(d);
    r = r * (2.0f - d * r);                                     // NR refine
    return (t - 1.0f) * r;
}

#define MFMA(acc, a, b) acc = __builtin_amdgcn_mfma_f32_16x16x32_bf16(a, b, acc, 0, 0, 0)

// ---------------------------------------------------------------------------
// fp32 weight -> bf16 hi + bf16 lo-residual MFMA B-fragment layout (as r4):
// frag elem = W[kt*32 + (lane>>4)*8 + j][nt*16 + (lane&15)]
// ---------------------------------------------------------------------------
__global__ void prep_kernel(const float* __restrict__ W,
                            unsigned short* __restrict__ dst,
                            int KT, int N, int total, int base, int wlimit){
    int tid = blockIdx.x * 256 + threadIdx.x;
    if (tid >= total) return;
    int j  = tid & 7;
    int l  = (tid >> 3) & 63;
    int t2 = tid >> 9;
    int kt = t2 % KT;
    int nt = t2 / KT;
    int row = kt * 32 + (l >> 4) * 8 + j;
    int col = nt * 16 + (l & 15);
    float w = W[(size_t)row * N + col];
    unsigned short h = f2bf(w);
    if (base + tid < wlimit)      dst[base + tid]      = h;
    if (base + LO + tid < wlimit) dst[base + LO + tid] = f2bf(w - bf2f(h));
}

// ---------------------------------------------------------------------------
// 5-MFMA fragment GEMM (A-triple from LDS x B-double from global).
// NW=4 waves; wave w handles pair-columns p = w, w+4, ...
// MODE 0: +bias -> zx (fp32 LDS)    MODE 1: +bias, softplus -> triple A-out
// MODE 4: +bias +x_last -> out fp32 global
// ---------------------------------------------------------------------------
template<int KT, int MODE>
static __device__ __forceinline__ void gemm5(
    const unsigned short* __restrict__ wf, int wbase, int npairs,
    const unsigned short* Ah, const unsigned short* Am, const unsigned short* Al,
    unsigned short* Aoh, unsigned short* Aom, unsigned short* Aol,
    float* zx,
    const float* __restrict__ bias_g,
    const float* __restrict__ xlast, float* __restrict__ outg, int bg)
{
    const int tid  = threadIdx.x;
    const int lane = tid & 63;
    const int wid  = tid >> 6;
    const int l15  = lane & 15;
    const int q    = lane >> 4;

    v8s ah[KT], am[KT], al[KT];
#pragma unroll
    for (int kt = 0; kt < KT; ++kt){
        ah[kt] = *(const v8s*)&Ah[l15 * AP + kt * 32 + q * 8];
        am[kt] = *(const v8s*)&Am[l15 * AP + kt * 32 + q * 8];
        al[kt] = *(const v8s*)&Al[l15 * AP + kt * 32 + q * 8];
    }

    for (int p = wid; p < npairs; p += 4){
        const int nt0 = 2 * p, nt1 = 2 * p + 1;
        v4f acc0 = {0.f, 0.f, 0.f, 0.f};
        v4f acc1 = {0.f, 0.f, 0.f, 0.f};
#pragma unroll
        for (int kt = 0; kt < KT; ++kt){
            int o0 = wbase + ((nt0 * KT + kt) * 64 + lane) * 8;
            int o1 = wbase + ((nt1 * KT + kt) * 64 + lane) * 8;
            v8s bh0 = *(const v8s*)&wf[o0];
            v8s bl0 = *(const v8s*)&wf[o0 + LO];
            v8s bh1 = *(const v8s*)&wf[o1];
            v8s bl1 = *(const v8s*)&wf[o1 + LO];
            MFMA(acc0, ah[kt], bh0); MFMA(acc0, am[kt], bh0); MFMA(acc0, al[kt], bh0);
            MFMA(acc0, ah[kt], bl0); MFMA(acc0, am[kt], bl0);
            MFMA(acc1, ah[kt], bh1); MFMA(acc1, am[kt], bh1); MFMA(acc1, al[kt], bh1);
            MFMA(acc1, ah[kt], bl1); MFMA(acc1, am[kt], bl1);
        }
        const int c0 = nt0 * 16 + l15, c1 = nt1 * 16 + l15;

        if (MODE == 0){
#pragma unroll
            for (int r = 0; r < 4; ++r){
                int b = q * 4 + r;
                zx[b * 128 + c0] = acc0[r] + bias_g[c0];
                zx[b * 128 + c1] = acc1[r] + bias_g[c1];
            }
        } else if (MODE == 1){
#pragma unroll
            for (int r = 0; r < 4; ++r){
                int b = q * 4 + r;
                float v0 = softplus_f(acc0[r] + bias_g[c0]);
                float v1 = softplus_f(acc1[r] + bias_g[c1]);
                unsigned short h, m, l;
                split3(v0, h, m, l); Aoh[b*AP+c0]=h; Aom[b*AP+c0]=m; Aol[b*AP+c0]=l;
                split3(v1, h, m, l); Aoh[b*AP+c1]=h; Aom[b*AP+c1]=m; Aol[b*AP+c1]=l;
            }
        } else { // MODE 4
#pragma unroll
            for (int r = 0; r < 4; ++r){
                int b = q * 4 + r, gb = bg * 16 + b;
                outg[gb * 32 + c0] = acc0[r] + bias_g[c0] + xlast[gb * 32 + c0];
                outg[gb * 32 + c1] = acc1[r] + bias_g[c1] + xlast[gb * 32 + c1];
            }
        }
    }
}

// ---------------------------------------------------------------------------
// Persistent team kernel: 256 blocks = 16 batch-groups x 16-block teams.
// Block (bg, tr) owns W3 columns [tr*256, tr*256+256) = h in [tr*8, tr*8+8),
// register-cached (hi+lo). Per stage: replicate W1/W2, compute own k-slice,
// exchange via global kbuf + monotone team counter, private RK4 update.
// ---------------------------------------------------------------------------
__global__ __launch_bounds__(256) void cde_kernel(
    const float* __restrict__ coeffs,
    const float* __restrict__ x_last,
    const float* __restrict__ bi,
    const float* __restrict__ b1,
    const float* __restrict__ b2,
    const float* __restrict__ b3,
    const float* __restrict__ br,
    const unsigned short* __restrict__ wf,
    float* __restrict__ kbuf,
    unsigned int* __restrict__ cntb,
    float* __restrict__ outg)
{
    __shared__ unsigned short A0h[16*AP] __attribute__((aligned(16)));
    __shared__ unsigned short A0m[16*AP] __attribute__((aligned(16)));
    __shared__ unsigned short A0l[16*AP] __attribute__((aligned(16)));
    __shared__ unsigned short A1h[16*AP] __attribute__((aligned(16)));
    __shared__ unsigned short A1m[16*AP] __attribute__((aligned(16)));
    __shared__ unsigned short A1l[16*AP] __attribute__((aligned(16)));
    __shared__ unsigned short A2h[16*AP] __attribute__((aligned(16)));
    __shared__ unsigned short A2m[16*AP] __attribute__((aligned(16)));
    __shared__ unsigned short A2l[16*AP] __attribute__((aligned(16)));
    __shared__ float dval[512];
    __shared__ float zx[2048];

    const int tid  = threadIdx.x;
    const int lane = tid & 63;
    const int wid  = tid >> 6;
    const int l15  = lane & 15;
    const int q    = lane >> 4;
    const int bx   = blockIdx.x;
    const int bg   = (bx & 7) * 2 + (bx >> 7);   // team members share bx%8 (XCD)
    const int tr   = (bx >> 3) & 15;

    float*        kb0 = kbuf + bg * 4096;        // [par][2048]
    unsigned int* cnt = cntb + bg * 8;           // 32 B spacing

    for (int e = tid; e < 16*AP; e += 256){
        A0h[e]=0; A0m[e]=0; A0l[e]=0; A1h[e]=0; A1m[e]=0; A1l[e]=0;
        A2h[e]=0; A2m[e]=0; A2l[e]=0;
    }

    // preload this block's W3 slice fragments (hi+lo) into registers
    v8s w3h[2][2][4], w3l[2][2][4];   // [pi][nt-in-pair][kt]
#pragma unroll
    for (int pi = 0; pi < 2; ++pi){
        int p = wid + 4 * pi;
#pragma unroll
        for (int i = 0; i < 2; ++i){
            int ntg = tr * 16 + 2 * p + i;
#pragma unroll
            for (int kt = 0; kt < 4; ++kt){
                int o = ((ntg * 4 + kt) * 64 + lane) * 8;   // OFF_W3 = 0
                w3h[pi][i][kt] = *(const v8s*)&wf[o];
                w3l[pi][i][kt] = *(const v8s*)&wf[o + LO];
            }
        }
    }

    // initial A0 = a0 = coeffs[:, 0, 0:32], triple-split
    for (int e = tid; e < 512; e += 256){
        int r = e >> 5, c = e & 31;
        float v = coeffs[((size_t)(bg * 16 + r) * 64) * 128 + c];
        unsigned short h, m, l; split3(v, h, m, l);
        A0h[r*AP+c] = h; A0m[r*AP+c] = m; A0l[r*AP+c] = l;
    }
    __syncthreads();
    gemm5<1, 0>(wf, OFF_WI, 4, A0h, A0m, A0l, nullptr, nullptr, nullptr,
                zx, bi, nullptr, nullptr, bg);
    __syncthreads();

    // thread-private RK4 state, e-partition: thread owns elems e = tid*8 .. +7
    float zp[8], kap[8], k1p[8], k2p[8];
#pragma unroll
    for (int i = 0; i < 8; ++i){ zp[i] = zx[tid*8 + i]; kap[i]=0.f; k1p[i]=0.f; k2p[i]=0.f; }

    const int arow = tid >> 4;           // (tid*8)>>7
    const int acol = (tid & 15) * 8;     // (tid*8)&127

    for (int st = 0; st < 256; ++st){
        const int stp = st >> 2, sub = st & 3;
        int idx; float frac;
        if      (sub == 0){ idx = stp; frac = 0.f; }
        else if (sub == 1){ idx = stp; frac = 1.f / 3.f; }
        else if (sub == 2){ idx = stp; frac = 2.f / 3.f; }
        else { idx = (stp < 63) ? stp + 1 : 63; frac = (stp < 63) ? 0.f : 1.f; }

        // spline derivative (exact fp32)
        for (int e = tid; e < 512; e += 256){
            int r = e >> 5, c = e & 31;
            size_t base = ((size_t)(bg * 16 + r) * 64 + idx) * 128;
            dval[e] = coeffs[base + 32 + c]
                    + (coeffs[base + 64 + c] + coeffs[base + 96 + c] * frac) * frac;
        }
        // stage A0 from private state (vectorized 16B LDS stores)
        {
            v8s vh, vm, vl;
#pragma unroll
            for (int i = 0; i < 8; ++i){
                float v = (sub == 0) ? zp[i] : kap[i];
                unsigned short h, m, l; split3(v, h, m, l);
                vh[i] = (short)h; vm[i] = (short)m; vl[i] = (short)l;
            }
            *(v8s*)&A0h[arow*AP + acol] = vh;
            *(v8s*)&A0m[arow*AP + acol] = vm;
            *(v8s*)&A0l[arow*AP + acol] = vl;
        }
        __syncthreads();
        gemm5<4, 1>(wf, OFF_W1, 4, A0h, A0m, A0l, A1h, A1m, A1l,
                    nullptr, b1, nullptr, nullptr, bg);
        __syncthreads();
        gemm5<4, 1>(wf, OFF_W2, 4, A1h, A1m, A1l, A2h, A2m, A2l,
                    nullptr, b2, nullptr, nullptr, bg);
        __syncthreads();

        // W3 slice with register B-fragments -> k slice
        const int par = st & 1;
        float* kbw = kb0 + par * 2048;
        {
            v8s ah[4], am[4], al[4];
#pragma unroll
            for (int kt = 0; kt < 4; ++kt){
                ah[kt] = *(const v8s*)&A2h[l15*AP + kt*32 + q*8];
                am[kt] = *(const v8s*)&A2m[l15*AP + kt*32 + q*8];
                al[kt] = *(const v8s*)&A2l[l15*AP + kt*32 + q*8];
            }
            float dv0[4], dv1[4];
#pragma unroll
            for (int r = 0; r < 4; ++r){
                dv0[r] = dval[(q*4 + r) * 32 + l15];
                dv1[r] = dval[(q*4 + r) * 32 + 16 + l15];
            }
#pragma unroll
            for (int pi = 0; pi < 2; ++pi){
                int p = wid + 4 * pi;
                v4f acc0 = {0.f,0.f,0.f,0.f}, acc1 = {0.f,0.f,0.f,0.f};
#pragma unroll
                for (int kt = 0; kt < 4; ++kt){
                    MFMA(acc0, ah[kt], w3h[pi][0][kt]); MFMA(acc0, am[kt], w3h[pi][0][kt]);
                    MFMA(acc0, al[kt], w3h[pi][0][kt]);
                    MFMA(acc0, ah[kt], w3l[pi][0][kt]); MFMA(acc0, am[kt], w3l[pi][0][kt]);
                    MFMA(acc1, ah[kt], w3h[pi][1][kt]); MFMA(acc1, am[kt], w3h[pi][1][kt]);
                    MFMA(acc1, al[kt], w3h[pi][1][kt]);
                    MFMA(acc1, ah[kt], w3l[pi][1][kt]); MFMA(acc1, am[kt], w3l[pi][1][kt]);
                }
                const int cg0 = tr * 256 + p * 32 + l15;   // global W3 col
                float s[4];
#pragma unroll
                for (int r = 0; r < 4; ++r){
                    float u0 = acc0[r] + b3[cg0];
                    float u1 = acc1[r] + b3[cg0 + 16];
                    s[r] = tanh_f(u0) * dv0[r] + tanh_f(u1) * dv1[r];
                }
#pragma unroll
                for (int sm = 1; sm <= 8; sm <<= 1){
#pragma unroll
                    for (int r = 0; r < 4; ++r) s[r] += __shfl_xor(s[r], sm);
                }
                if (l15 == 0){
#pragma unroll
                    for (int r = 0; r < 4; ++r)
                        kbw[(q*4 + r) * 128 + tr * 8 + p] = s[r];
                }
            }
        }
        // team exchange: publish slice, wait for 16 publishes, read full k
        __threadfence();
        __syncthreads();
        if (tid == 0){
            atomicAdd(cnt, 1u);
            unsigned target = 16u * (unsigned)(st + 1);
            unsigned it = 0;
            while (__hip_atomic_load(cnt, __ATOMIC_ACQUIRE, __HIP_MEMORY_SCOPE_AGENT) < target
                   && ++it < (1u << 22))
                __builtin_amdgcn_s_sleep(2);
        }
        __syncthreads();
        __threadfence();

        float kv[8];
#pragma unroll
        for (int i = 0; i < 8; ++i)
            kv[i] = __hip_atomic_load(&kbw[tid*8 + i], __ATOMIC_RELAXED,
                                      __HIP_MEMORY_SCOPE_AGENT);
#pragma unroll
        for (int i = 0; i < 8; ++i){
            float k = kv[i];
            if      (sub == 0){ k1p[i] = k; kap[i] = zp[i] + k * (1.f/3.f); }
            else if (sub == 1){ k2p[i] = k; kap[i] = zp[i] + (k - k1p[i] * (1.f/3.f)); }
            else if (sub == 2){ kap[i] = zp[i] + (k1p[i] - k2p[i] + k); }
            else { zp[i] = zp[i] + (6.f*k2p[i] - 2.f*k1p[i]
                                    + 3.f*(kap[i] - zp[i]) + k) * 0.125f; }
        }
    }

    // out = x_last + z @ Wr + br  (every team block writes identical values)
    {
        v8s vh, vm, vl;
#pragma unroll
        for (int i = 0; i < 8; ++i){
            unsigned short h, m, l; split3(zp[i], h, m, l);
            vh[i] = (short)h; vm[i] = (short)m; vl[i] = (short)l;
        }
        *(v8s*)&A0h[arow*AP + acol] = vh;
        *(v8s*)&A0m[arow*AP + acol] = vm;
        *(v8s*)&A0l[arow*AP + acol] = vl;
    }
    __syncthreads();
    gemm5<4, 4>(wf, OFF_WR, 1, A0h, A0m, A0l, nullptr, nullptr, nullptr,
                nullptr, br, x_last, outg, bg);
}

extern "C" void kernel_launch(void* const* d_in, const int* in_sizes, int n_in,
                              void* d_out, int out_size, void* d_ws, size_t ws_size,
                              hipStream_t stream)
{
    const float* coeffs = (const float*)d_in[0];
    const float* x_last = (const float*)d_in[1];
    const float* Wi     = (const float*)d_in[2];
    const float* bi     = (const float*)d_in[3];
    const float* W1     = (const float*)d_in[4];
    const float* b1     = (const float*)d_in[5];
    const float* W2     = (const float*)d_in[6];
    const float* b2     = (const float*)d_in[7];
    const float* W3     = (const float*)d_in[8];
    const float* b3     = (const float*)d_in[9];
    const float* Wr     = (const float*)d_in[10];
    const float* br     = (const float*)d_in[11];
    unsigned short* wf  = (unsigned short*)d_ws;
    float*        kbuf  = (float*)((char*)d_ws + KBUF_BYTE);
    unsigned int* cntb  = (unsigned int*)((char*)d_ws + CNT_BYTE);

    size_t wcap = ws_size / 2;
    int wl = (wcap > (size_t)WF_TOTAL2) ? WF_TOTAL2 : (int)wcap;

    prep_kernel<<<(524288 + 255) / 256, 256, 0, stream>>>(W3, wf, 4, 4096, 524288, OFF_W3, wl);
    prep_kernel<<<(4096   + 255) / 256, 256, 0, stream>>>(Wi, wf, 1, 128,  4096,   OFF_WI, wl);
    prep_kernel<<<(16384  + 255) / 256, 256, 0, stream>>>(W1, wf, 4, 128,  16384,  OFF_W1, wl);
    prep_kernel<<<(16384  + 255) / 256, 256, 0, stream>>>(W2, wf, 4, 128,  16384,  OFF_W2, wl);
    prep_kernel<<<(4096   + 255) / 256, 256, 0, stream>>>(Wr, wf, 4, 32,   4096,   OFF_WR, wl);
    hipMemsetAsync((char*)d_ws + CNT_BYTE, 0, 512, stream);   // zero team counters

    cde_kernel<<<256, 256, 0, stream>>>(coeffs, x_last, bi, b1, b2, b3, br, wf,
                                        kbuf, cntb, (float*)d_out);
}

// Round 6
// 2552.646 us; speedup vs baseline: 5.2308x; 5.2308x over previous
//
#include <hip/hip_runtime.h>
#include <math.h>

typedef __attribute__((ext_vector_type(8))) short v8s;
typedef __attribute__((ext_vector_type(4))) float v4f;

#define AP 136              // padded LDS row stride (shorts); 272 B rows keep 16B align
#define OFF_W3 0
#define OFF_WI 524288
#define OFF_W1 528384
#define OFF_W2 544768
#define OFF_WR 561152
#define LO     565248       // lo-residual region offset (shorts)
#define WF_TOTAL2 1130496   // hi+lo regions (shorts, 2.26 MB)
#define KBUF_BYTE 2260992   // float kbuf[16 bg][2 par][2048]  (256 KB)
#define FLG_BYTE  2523136   // uint flags[16 bg][16 tr] @ 128 B spacing (32 KB)
#define FLG_SIZE  32768

static __device__ __forceinline__ float bf2f(unsigned short s){
    union { unsigned u; float f; } v; v.u = ((unsigned)s) << 16; return v.f;
}
static __device__ __forceinline__ unsigned short f2bf(float f){
    union { float ff; unsigned u; } v; v.ff = f;
    return (unsigned short)((v.u + 0x7FFFu + ((v.u >> 16) & 1u)) >> 16);
}
// triple split: v = h + m + l + eps, |eps| <= 2^-27 |v|
static __device__ __forceinline__ void split3(float v, unsigned short& h,
                                              unsigned short& m, unsigned short& l){
    h = f2bf(v);  float r1 = v - bf2f(h);
    m = f2bf(r1); float r2 = r1 - bf2f(m);
    l = f2bf(r2);
}
static __device__ __forceinline__ float softplus_f(float x){
    // ln(1+e^x) = ln2 * log2(1 + 2^(x*log2e)), HW exp2/log2 (~1 ulp)
    float t = __builtin_amdgcn_exp2f(x * 1.44269504088896341f);
    float r = 0.69314718055994531f * __builtin_amdgcn_logf(1.0f + t);
    return (x > 20.0f) ? x : r;
}
static __device__ __forceinline__ float tanh_f(float x){
    float xc = fminf(fmaxf(x, -9.0f), 9.0f);
    float t = __builtin_amdgcn_exp2f(xc * 2.8853900817779268f); // e^{2x}
    float d = t + 1.0f;
    float r = __builtin_amdgcn_rcpf(d);
    r = r * (2.0f - d * r);                                     // NR refine
    return (t - 1.0f) * r;
}

#define MFMA(acc, a, b) acc = __builtin_amdgcn_mfma_f32_16x16x32_bf16(a, b, acc, 0, 0, 0)

// ---------------------------------------------------------------------------
// fp32 weight -> bf16 hi + bf16 lo-residual MFMA B-fragment layout:
// frag elem = W[kt*32 + (lane>>4)*8 + j][nt*16 + (lane&15)]
// ---------------------------------------------------------------------------
__global__ void prep_kernel(const float* __restrict__ W,
                            unsigned short* __restrict__ dst,
                            int KT, int N, int total, int base, int wlimit){
    int tid = blockIdx.x * 256 + threadIdx.x;
    if (tid >= total) return;
    int j  = tid & 7;
    int l  = (tid >> 3) & 63;
    int t2 = tid >> 9;
    int kt = t2 % KT;
    int nt = t2 / KT;
    int row = kt * 32 + (l >> 4) * 8 + j;
    int col = nt * 16 + (l & 15);
    float w = W[(size_t)row * N + col];
    unsigned short h = f2bf(w);
    if (base + tid < wlimit)      dst[base + tid]      = h;
    if (base + LO + tid < wlimit) dst[base + LO + tid] = f2bf(w - bf2f(h));
}

// ---------------------------------------------------------------------------
// 5-MFMA fragment GEMM (A-triple from LDS x B-double from global).
// 4 waves; wave w handles pair-columns p = w, w+4, ...
// MODE 0: +bias -> zx (fp32 LDS)    MODE 1: +bias, softplus -> triple A-out
// MODE 4: +bias +x_last -> out fp32 global
// ---------------------------------------------------------------------------
template<int KT, int MODE>
static __device__ __forceinline__ void gemm5(
    const unsigned short* __restrict__ wf, int wbase, int npairs,
    const unsigned short* Ah, const unsigned short* Am, const unsigned short* Al,
    unsigned short* Aoh, unsigned short* Aom, unsigned short* Aol,
    float* zx,
    const float* __restrict__ bias_g,
    const float* __restrict__ xlast, float* __restrict__ outg, int bg)
{
    const int tid  = threadIdx.x;
    const int lane = tid & 63;
    const int wid  = tid >> 6;
    const int l15  = lane & 15;
    const int q    = lane >> 4;

    v8s ah[KT], am[KT], al[KT];
#pragma unroll
    for (int kt = 0; kt < KT; ++kt){
        ah[kt] = *(const v8s*)&Ah[l15 * AP + kt * 32 + q * 8];
        am[kt] = *(const v8s*)&Am[l15 * AP + kt * 32 + q * 8];
        al[kt] = *(const v8s*)&Al[l15 * AP + kt * 32 + q * 8];
    }

    for (int p = wid; p < npairs; p += 4){
        const int nt0 = 2 * p, nt1 = 2 * p + 1;
        v4f acc0 = {0.f, 0.f, 0.f, 0.f};
        v4f acc1 = {0.f, 0.f, 0.f, 0.f};
#pragma unroll
        for (int kt = 0; kt < KT; ++kt){
            int o0 = wbase + ((nt0 * KT + kt) * 64 + lane) * 8;
            int o1 = wbase + ((nt1 * KT + kt) * 64 + lane) * 8;
            v8s bh0 = *(const v8s*)&wf[o0];
            v8s bl0 = *(const v8s*)&wf[o0 + LO];
            v8s bh1 = *(const v8s*)&wf[o1];
            v8s bl1 = *(const v8s*)&wf[o1 + LO];
            MFMA(acc0, ah[kt], bh0); MFMA(acc0, am[kt], bh0); MFMA(acc0, al[kt], bh0);
            MFMA(acc0, ah[kt], bl0); MFMA(acc0, am[kt], bl0);
            MFMA(acc1, ah[kt], bh1); MFMA(acc1, am[kt], bh1); MFMA(acc1, al[kt], bh1);
            MFMA(acc1, ah[kt], bl1); MFMA(acc1, am[kt], bl1);
        }
        const int c0 = nt0 * 16 + l15, c1 = nt1 * 16 + l15;

        if (MODE == 0){
#pragma unroll
            for (int r = 0; r < 4; ++r){
                int b = q * 4 + r;
                zx[b * 128 + c0] = acc0[r] + bias_g[c0];
                zx[b * 128 + c1] = acc1[r] + bias_g[c1];
            }
        } else if (MODE == 1){
#pragma unroll
            for (int r = 0; r < 4; ++r){
                int b = q * 4 + r;
                float v0 = softplus_f(acc0[r] + bias_g[c0]);
                float v1 = softplus_f(acc1[r] + bias_g[c1]);
                unsigned short h, m, l;
                split3(v0, h, m, l); Aoh[b*AP+c0]=h; Aom[b*AP+c0]=m; Aol[b*AP+c0]=l;
                split3(v1, h, m, l); Aoh[b*AP+c1]=h; Aom[b*AP+c1]=m; Aol[b*AP+c1]=l;
            }
        } else { // MODE 4
#pragma unroll
            for (int r = 0; r < 4; ++r){
                int b = q * 4 + r, gb = bg * 16 + b;
                outg[gb * 32 + c0] = acc0[r] + bias_g[c0] + xlast[gb * 32 + c0];
                outg[gb * 32 + c1] = acc1[r] + bias_g[c1] + xlast[gb * 32 + c1];
            }
        }
    }
}

// ---------------------------------------------------------------------------
// Persistent team kernel: 256 blocks = 16 batch-groups x 16-block teams.
// Block (bg, tr) owns W3 columns [tr*256, tr*256+256), register-cached.
// Per stage: replicate W1/W2, compute own k-slice, publish via agent-scope
// atomic stores + per-producer monotone flag; relaxed-poll the 16 flags.
// ---------------------------------------------------------------------------
__global__ __launch_bounds__(256) void cde_kernel(
    const float* __restrict__ coeffs,
    const float* __restrict__ x_last,
    const float* __restrict__ bi,
    const float* __restrict__ b1,
    const float* __restrict__ b2,
    const float* __restrict__ b3,
    const float* __restrict__ br,
    const unsigned short* __restrict__ wf,
    float* __restrict__ kbuf,
    unsigned int* __restrict__ flgs,
    float* __restrict__ outg)
{
    __shared__ unsigned short A0h[16*AP] __attribute__((aligned(16)));
    __shared__ unsigned short A0m[16*AP] __attribute__((aligned(16)));
    __shared__ unsigned short A0l[16*AP] __attribute__((aligned(16)));
    __shared__ unsigned short A1h[16*AP] __attribute__((aligned(16)));
    __shared__ unsigned short A1m[16*AP] __attribute__((aligned(16)));
    __shared__ unsigned short A1l[16*AP] __attribute__((aligned(16)));
    __shared__ unsigned short A2h[16*AP] __attribute__((aligned(16)));
    __shared__ unsigned short A2m[16*AP] __attribute__((aligned(16)));
    __shared__ unsigned short A2l[16*AP] __attribute__((aligned(16)));
    __shared__ float dval[512];
    __shared__ float zx[2048];

    const int tid  = threadIdx.x;
    const int lane = tid & 63;
    const int wid  = tid >> 6;
    const int l15  = lane & 15;
    const int q    = lane >> 4;
    const int bx   = blockIdx.x;
    const int bg   = (bx & 7) * 2 + (bx >> 7);   // team members share bx%8 (XCD)
    const int tr   = (bx >> 3) & 15;

    float*        kb0     = kbuf + bg * 4096;    // [par][2048]
    unsigned int* teamflg = flgs + bg * 16 * 32; // 128 B per flag line
    unsigned int* myflag  = teamflg + tr * 32;

    for (int e = tid; e < 16*AP; e += 256){
        A0h[e]=0; A0m[e]=0; A0l[e]=0; A1h[e]=0; A1m[e]=0; A1l[e]=0;
        A2h[e]=0; A2m[e]=0; A2l[e]=0;
    }

    // preload this block's W3 slice fragments (hi+lo) into registers
    v8s w3h[2][2][4], w3l[2][2][4];   // [pi][nt-in-pair][kt]
#pragma unroll
    for (int pi = 0; pi < 2; ++pi){
        int p = wid + 4 * pi;
#pragma unroll
        for (int i = 0; i < 2; ++i){
            int ntg = tr * 16 + 2 * p + i;
#pragma unroll
            for (int kt = 0; kt < 4; ++kt){
                int o = ((ntg * 4 + kt) * 64 + lane) * 8;   // OFF_W3 = 0
                w3h[pi][i][kt] = *(const v8s*)&wf[o];
                w3l[pi][i][kt] = *(const v8s*)&wf[o + LO];
            }
        }
    }

    // initial A0 = a0 = coeffs[:, 0, 0:32], triple-split
    for (int e = tid; e < 512; e += 256){
        int r = e >> 5, c = e & 31;
        float v = coeffs[((size_t)(bg * 16 + r) * 64) * 128 + c];
        unsigned short h, m, l; split3(v, h, m, l);
        A0h[r*AP+c] = h; A0m[r*AP+c] = m; A0l[r*AP+c] = l;
    }
    __syncthreads();
    gemm5<1, 0>(wf, OFF_WI, 4, A0h, A0m, A0l, nullptr, nullptr, nullptr,
                zx, bi, nullptr, nullptr, bg);
    __syncthreads();

    // thread-private RK4 state: thread owns elems e = tid*8 .. +7
    float zp[8], kap[8], k1p[8], k2p[8];
#pragma unroll
    for (int i = 0; i < 8; ++i){ zp[i] = zx[tid*8 + i]; kap[i]=0.f; k1p[i]=0.f; k2p[i]=0.f; }

    const int arow = tid >> 4;
    const int acol = (tid & 15) * 8;

    for (int st = 0; st < 256; ++st){
        const int stp = st >> 2, sub = st & 3;
        int idx; float frac;
        if      (sub == 0){ idx = stp; frac = 0.f; }
        else if (sub == 1){ idx = stp; frac = 1.f / 3.f; }
        else if (sub == 2){ idx = stp; frac = 2.f / 3.f; }
        else { idx = (stp < 63) ? stp + 1 : 63; frac = (stp < 63) ? 0.f : 1.f; }

        // spline derivative (exact fp32)
        for (int e = tid; e < 512; e += 256){
            int r = e >> 5, c = e & 31;
            size_t base = ((size_t)(bg * 16 + r) * 64 + idx) * 128;
            dval[e] = coeffs[base + 32 + c]
                    + (coeffs[base + 64 + c] + coeffs[base + 96 + c] * frac) * frac;
        }
        // stage A0 from private state (vectorized 16B LDS stores)
        {
            v8s vh, vm, vl;
#pragma unroll
            for (int i = 0; i < 8; ++i){
                float v = (sub == 0) ? zp[i] : kap[i];
                unsigned short h, m, l; split3(v, h, m, l);
                vh[i] = (short)h; vm[i] = (short)m; vl[i] = (short)l;
            }
            *(v8s*)&A0h[arow*AP + acol] = vh;
            *(v8s*)&A0m[arow*AP + acol] = vm;
            *(v8s*)&A0l[arow*AP + acol] = vl;
        }
        __syncthreads();
        gemm5<4, 1>(wf, OFF_W1, 4, A0h, A0m, A0l, A1h, A1m, A1l,
                    nullptr, b1, nullptr, nullptr, bg);
        __syncthreads();
        gemm5<4, 1>(wf, OFF_W2, 4, A1h, A1m, A1l, A2h, A2m, A2l,
                    nullptr, b2, nullptr, nullptr, bg);
        __syncthreads();

        // W3 slice with register B-fragments -> k slice
        const int par = st & 1;
        float* kbw = kb0 + par * 2048;
        {
            v8s ah[4], am[4], al[4];
#pragma unroll
            for (int kt = 0; kt < 4; ++kt){
                ah[kt] = *(const v8s*)&A2h[l15*AP + kt*32 + q*8];
                am[kt] = *(const v8s*)&A2m[l15*AP + kt*32 + q*8];
                al[kt] = *(const v8s*)&A2l[l15*AP + kt*32 + q*8];
            }
            float dv0[4], dv1[4];
#pragma unroll
            for (int r = 0; r < 4; ++r){
                dv0[r] = dval[(q*4 + r) * 32 + l15];
                dv1[r] = dval[(q*4 + r) * 32 + 16 + l15];
            }
#pragma unroll
            for (int pi = 0; pi < 2; ++pi){
                int p = wid + 4 * pi;
                v4f acc0 = {0.f,0.f,0.f,0.f}, acc1 = {0.f,0.f,0.f,0.f};
#pragma unroll
                for (int kt = 0; kt < 4; ++kt){
                    MFMA(acc0, ah[kt], w3h[pi][0][kt]); MFMA(acc0, am[kt], w3h[pi][0][kt]);
                    MFMA(acc0, al[kt], w3h[pi][0][kt]);
                    MFMA(acc0, ah[kt], w3l[pi][0][kt]); MFMA(acc0, am[kt], w3l[pi][0][kt]);
                    MFMA(acc1, ah[kt], w3h[pi][1][kt]); MFMA(acc1, am[kt], w3h[pi][1][kt]);
                    MFMA(acc1, al[kt], w3h[pi][1][kt]);
                    MFMA(acc1, ah[kt], w3l[pi][1][kt]); MFMA(acc1, am[kt], w3l[pi][1][kt]);
                }
                const int cg0 = tr * 256 + p * 32 + l15;   // global W3 col
                float s[4];
#pragma unroll
                for (int r = 0; r < 4; ++r){
                    float u0 = acc0[r] + b3[cg0];
                    float u1 = acc1[r] + b3[cg0 + 16];
                    s[r] = tanh_f(u0) * dv0[r] + tanh_f(u1) * dv1[r];
                }
#pragma unroll
                for (int sm = 1; sm <= 8; sm <<= 1){
#pragma unroll
                    for (int r = 0; r < 4; ++r) s[r] += __shfl_xor(s[r], sm);
                }
                if (l15 == 0){
#pragma unroll
                    for (int r = 0; r < 4; ++r)
                        __hip_atomic_store(&kbw[(q*4 + r) * 128 + tr * 8 + p], s[r],
                                           __ATOMIC_RELAXED, __HIP_MEMORY_SCOPE_AGENT);
                }
            }
        }
        // publish: barrier drains all waves' vmcnt; one release flag store
        __syncthreads();
        if (tid == 0)
            __hip_atomic_store(myflag, (unsigned)(st + 1),
                               __ATOMIC_RELEASE, __HIP_MEMORY_SCOPE_AGENT);
        // wait: threads 0..15 poll the 16 producer flags (relaxed, cheap)
        if (tid < 16){
            const unsigned tgt = (unsigned)(st + 1);
            unsigned it = 0;
            while (__hip_atomic_load(&teamflg[tid * 32], __ATOMIC_RELAXED,
                                     __HIP_MEMORY_SCOPE_AGENT) < tgt
                   && ++it < (1u << 22))
                __builtin_amdgcn_s_sleep(1);
        }
        __syncthreads();

        float kv[8];
#pragma unroll
        for (int i = 0; i < 8; ++i)
            kv[i] = __hip_atomic_load(&kbw[tid*8 + i], __ATOMIC_RELAXED,
                                      __HIP_MEMORY_SCOPE_AGENT);
#pragma unroll
        for (int i = 0; i < 8; ++i){
            float k = kv[i];
            if      (sub == 0){ k1p[i] = k; kap[i] = zp[i] + k * (1.f/3.f); }
            else if (sub == 1){ k2p[i] = k; kap[i] = zp[i] + (k - k1p[i] * (1.f/3.f)); }
            else if (sub == 2){ kap[i] = zp[i] + (k1p[i] - k2p[i] + k); }
            else { zp[i] = zp[i] + (6.f*k2p[i] - 2.f*k1p[i]
                                    + 3.f*(kap[i] - zp[i]) + k) * 0.125f; }
        }
    }

    // out = x_last + z @ Wr + br  (every team block writes identical values)
    {
        v8s vh, vm, vl;
#pragma unroll
        for (int i = 0; i < 8; ++i){
            unsigned short h, m, l; split3(zp[i], h, m, l);
            vh[i] = (short)h; vm[i] = (short)m; vl[i] = (short)l;
        }
        *(v8s*)&A0h[arow*AP + acol] = vh;
        *(v8s*)&A0m[arow*AP + acol] = vm;
        *(v8s*)&A0l[arow*AP + acol] = vl;
    }
    __syncthreads();
    gemm5<4, 4>(wf, OFF_WR, 1, A0h, A0m, A0l, nullptr, nullptr, nullptr,
                nullptr, br, x_last, outg, bg);
}

extern "C" void kernel_launch(void* const* d_in, const int* in_sizes, int n_in,
                              void* d_out, int out_size, void* d_ws, size_t ws_size,
                              hipStream_t stream)
{
    const float* coeffs = (const float*)d_in[0];
    const float* x_last = (const float*)d_in[1];
    const float* Wi     = (const float*)d_in[2];
    const float* bi     = (const float*)d_in[3];
    const float* W1     = (const float*)d_in[4];
    const float* b1     = (const float*)d_in[5];
    const float* W2     = (const float*)d_in[6];
    const float* b2     = (const float*)d_in[7];
    const float* W3     = (const float*)d_in[8];
    const float* b3     = (const float*)d_in[9];
    const float* Wr     = (const float*)d_in[10];
    const float* br     = (const float*)d_in[11];
    unsigned short* wf  = (unsigned short*)d_ws;
    float*        kbuf  = (float*)((char*)d_ws + KBUF_BYTE);
    unsigned int* flgs  = (unsigned int*)((char*)d_ws + FLG_BYTE);

    size_t wcap = ws_size / 2;
    int wl = (wcap > (size_t)WF_TOTAL2) ? WF_TOTAL2 : (int)wcap;

    prep_kernel<<<(524288 + 255) / 256, 256, 0, stream>>>(W3, wf, 4, 4096, 524288, OFF_W3, wl);
    prep_kernel<<<(4096   + 255) / 256, 256, 0, stream>>>(Wi, wf, 1, 128,  4096,   OFF_WI, wl);
    prep_kernel<<<(16384  + 255) / 256, 256, 0, stream>>>(W1, wf, 4, 128,  16384,  OFF_W1, wl);
    prep_kernel<<<(16384  + 255) / 256, 256, 0, stream>>>(W2, wf, 4, 128,  16384,  OFF_W2, wl);
    prep_kernel<<<(4096   + 255) / 256, 256, 0, stream>>>(Wr, wf, 4, 32,   4096,   OFF_WR, wl);
    hipMemsetAsync((char*)d_ws + FLG_BYTE, 0, FLG_SIZE, stream);   // zero flags

    cde_kernel<<<256, 256, 0, stream>>>(coeffs, x_last, bi, b1, b2, b3, br, wf,
                                        kbuf, flgs, (float*)d_out);
}